// Round 1
// baseline (3001.712 us; speedup 1.0000x reference)
//
#include <hip/hip_runtime.h>
#include <cmath>

constexpr int N_  = 20000;
constexpr int E_  = 320000;
constexpr int NE_ = 4;
constexpr int G_  = 16;
constexpr int CAP = 96;
constexpr float RMAXF = 5.0f;
constexpr float PI_F  = 3.14159265358979323846f;
constexpr float S3  = 1.7320508075688772f;
constexpr float S5  = 2.2360679774997896f;
constexpr float S15 = 3.8729833462074170f;

#define DEV static __device__ __forceinline__

// fallback scratch (440 MB) in case ws_size is too small
__device__ float g_fallback[110000000];

DEV float wsum(float v){
  #pragma unroll
  for (int o = 32; o > 0; o >>= 1) v += __shfl_xor(v, o, 64);
  return v;
}
DEV float sigmoidf_(float x){ return 1.0f/(1.0f+expf(-x)); }

// ---------------- CSR build (bucket lists, no scan) ----------------
__global__ void k_csr(const int* __restrict__ ei, int* __restrict__ cntR, int* __restrict__ cntS,
                      int* __restrict__ listR, int* __restrict__ listS){
  int e = blockIdx.x*256 + threadIdx.x;
  int s = ei[e], r = ei[E_+e];
  int p = atomicAdd(&cntR[r], 1); if (p < CAP) listR[r*CAP+p] = e;
  int q = atomicAdd(&cntS[s], 1); if (q < CAP) listS[s*CAP+q] = e;
}

// ---------------- geometry: Y, ef, u, r ----------------
__global__ void k_geom(const float* __restrict__ pos, const float* __restrict__ shifts,
                       const int* __restrict__ ei,
                       float* __restrict__ Y, float* __restrict__ ef,
                       float* __restrict__ u3, float* __restrict__ rr){
  int e = blockIdx.x*256 + threadIdx.x;
  int s = ei[e], r = ei[E_+e];
  float vx = pos[s*3+0]-pos[r*3+0]+shifts[e*3+0];
  float vy = pos[s*3+1]-pos[r*3+1]+shifts[e*3+1];
  float vz = pos[s*3+2]-pos[r*3+2]+shifts[e*3+2];
  float ss = vx*vx+vy*vy+vz*vz + 1e-12f;
  float rad = sqrtf(ss);
  float inv = 1.0f/rad;
  float x = vx*inv, y = vy*inv, z = vz*inv;
  u3[e*3+0]=x; u3[e*3+1]=y; u3[e*3+2]=z; rr[e]=rad;
  Y[e*9+0]=1.0f;
  Y[e*9+1]=S3*x;  Y[e*9+2]=S3*y;  Y[e*9+3]=S3*z;
  Y[e*9+4]=S15*x*y; Y[e*9+5]=S15*y*z;
  Y[e*9+6]=0.5f*S5*(3.0f*z*z-1.0f);
  Y[e*9+7]=S15*x*z;
  Y[e*9+8]=0.5f*S15*(x*x-y*y);
  float t = rad*(1.0f/RMAXF);
  float fc = 0.0f;
  if (t < 1.0f){
    float t2=t*t, t4=t2*t2, t6=t4*t2, t7=t6*t, t8=t7*t;
    fc = 1.0f - 28.0f*t6 + 48.0f*t7 - 21.0f*t8;
  }
  float Kc = sqrtf(2.0f/RMAXF);
  #pragma unroll
  for (int b=0;b<8;++b){
    float w = (float)(b+1)*(PI_F/RMAXF);
    ef[e*8+b] = Kc*sinf(w*rad)*inv*fc;
  }
}

// ---------------- tiny precompute: WembUp = W_embed @ Wup0 ----------------
__global__ void k_wembup(const float* __restrict__ Wemb, const float* __restrict__ Wup0,
                         float* __restrict__ WembUp){
  int t = threadIdx.x; int k = t>>6, c = t&63;
  float acc = 0.f;
  for (int j=0;j<64;++j) acc += Wemb[k*64+j]*Wup0[j*64+c];
  WembUp[k*64+c] = acc;
}

// ---------------- e0 ----------------
__global__ void k_e0(const float* __restrict__ attrs, const float* __restrict__ ae,
                     const int* __restrict__ batch, float* __restrict__ out){
  int n = blockIdx.x*256 + threadIdx.x; if (n >= N_) return;
  float v = 0.f;
  #pragma unroll
  for (int k=0;k<NE_;++k) v += attrs[n*NE_+k]*ae[k];
  int g = batch[n];
  atomicAdd(&out[g], v);
  atomicAdd(&out[G_ + g*3 + 0], v);
}

// ---------------- hu0 = attrs @ WembUp ----------------
__global__ void k_hu0(const float* __restrict__ attrs, const float* __restrict__ WembUp,
                      float* __restrict__ hu0){
  int i = blockIdx.x*256 + threadIdx.x;
  int n = i>>6, c = i&63;
  float acc = 0.f;
  #pragma unroll
  for (int k=0;k<NE_;++k) acc += attrs[n*NE_+k]*WembUp[k*64+c];
  hu0[i] = acc;
}

// ---------------- R = silu(ef@W1) @ W2, 4 edges per block ----------------
__global__ void k_R(const float* __restrict__ ef, const float* __restrict__ W1g,
                    const float* __restrict__ W2g, float* __restrict__ R){
  __shared__ float sW1[8*64];
  __shared__ float sW2[64*64];
  __shared__ float sA[4*64];
  int t = threadIdx.x;
  for (int i=t;i<512;i+=256)  sW1[i]=W1g[i];
  for (int i=t;i<4096;i+=256) sW2[i]=W2g[i];
  __syncthreads();
  int eg = t>>6, c = t&63;
  int e = blockIdx.x*4 + eg;
  float efv[8];
  #pragma unroll
  for (int b=0;b<8;++b) efv[b] = ef[e*8+b];
  float z = 0.f;
  #pragma unroll
  for (int b=0;b<8;++b) z += efv[b]*sW1[b*64+c];
  float a = z*sigmoidf_(z);
  sA[eg*64+c] = a;
  __syncthreads();
  float r = 0.f;
  #pragma unroll 16
  for (int k=0;k<64;++k) r += sA[eg*64+k]*sW2[k*64+c];
  R[e*64+c] = r;
}

// ---------------- agg0[n,l,c] = sum_e Y[e,l]*R0[e,c]*hu0[snd,c]  (wave/node) ----------------
__global__ void k_agg0(const int* __restrict__ cntR, const int* __restrict__ listR,
                       const int* __restrict__ ei, const float* __restrict__ hu0,
                       const float* __restrict__ R0, const float* __restrict__ Y,
                       float* __restrict__ agg0){
  int t = threadIdx.x; int n = blockIdx.x*4 + (t>>6); int c = t&63;
  float acc[9] = {0,0,0,0,0,0,0,0,0};
  int deg = min(cntR[n], CAP);
  for (int j=0;j<deg;++j){
    int e = listR[n*CAP+j];
    int s = ei[e];
    float p = R0[e*64+c]*hu0[s*64+c];
    #pragma unroll
    for (int l=0;l<9;++l) acc[l] += Y[e*9+l]*p;
  }
  #pragma unroll
  for (int l=0;l<9;++l) agg0[(n*9+l)*64+c] = acc[l];
}

// ---------------- agg1[n,c] = sum_e R1[e,c]*s1[e,c] (s1 computed on the fly) ----------------
__global__ void k_agg1(const int* __restrict__ cntR, const int* __restrict__ listR,
                       const int* __restrict__ ei, const float* __restrict__ hu1,
                       const float* __restrict__ R1, const float* __restrict__ Y,
                       float* __restrict__ agg1){
  int t = threadIdx.x; int n = blockIdx.x*4 + (t>>6); int c = t&63;
  float acc = 0.f;
  int deg = min(cntR[n], CAP);
  for (int j=0;j<deg;++j){
    int e = listR[n*CAP+j];
    int s = ei[e];
    float sacc = 0.f;
    #pragma unroll
    for (int l=0;l<9;++l) sacc += hu1[(s*9+l)*64+c]*Y[e*9+l];
    acc += R1[e*64+c]*sacc;
  }
  agg1[n*64+c] = acc;
}

// ---------------- dhu1[n,l,c] = sum_{snd-list} Y[e,l]*R1[e,c]*ga1[rcv,c] ----------------
__global__ void k_dhu1(const int* __restrict__ cntS, const int* __restrict__ listS,
                       const int* __restrict__ ei, const float* __restrict__ R1,
                       const float* __restrict__ ga1, const float* __restrict__ Y,
                       float* __restrict__ dhu1){
  int t = threadIdx.x; int n = blockIdx.x*4 + (t>>6); int c = t&63;
  float acc[9] = {0,0,0,0,0,0,0,0,0};
  int deg = min(cntS[n], CAP);
  for (int j=0;j<deg;++j){
    int e = listS[n*CAP+j];
    int r = ei[E_+e];
    float ds = R1[e*64+c]*ga1[r*64+c];
    #pragma unroll
    for (int l=0;l<9;++l) acc[l] += Y[e*9+l]*ds;
  }
  #pragma unroll
  for (int l=0;l<9;++l) dhu1[(n*9+l)*64+c] = acc[l];
}

// ---------------- generic 64x64 row-matmul, optional transpose/skip/bias ----------------
template<bool TRANS>
__global__ void k_mm64(const float* __restrict__ in, const float* __restrict__ W,
                       float* __restrict__ out, int rows, int lper,
                       const float* __restrict__ attrs, const float* __restrict__ Wsk,
                       const float* __restrict__ bias){
  __shared__ float sW[64*65];
  __shared__ float sRow[4*64];
  int t = threadIdx.x;
  for (int i=t;i<4096;i+=256){
    int k=i>>6, c=i&63;
    sW[k*65+c] = TRANS ? W[c*64+k] : W[k*64+c];
  }
  __syncthreads();
  int wid = t>>6, c = t&63;
  for (int it=0; it<8; ++it){
    int row = (blockIdx.x*8+it)*4 + wid;
    sRow[wid*64+c] = in[row*64+c];
    __syncthreads();
    float acc = 0.f;
    #pragma unroll 16
    for (int k=0;k<64;++k) acc += sRow[wid*64+k]*sW[k*65+c];
    if (lper==1 || (row % 9)==0){
      int n = (lper==1) ? row : (row/9);
      if (attrs){
        #pragma unroll
        for (int k=0;k<NE_;++k) acc += attrs[n*NE_+k]*Wsk[k*64+c];
      }
      if (bias) acc += bias[c];
    }
    out[row*64+c] = acc;
    __syncthreads();
  }
}

// ---------------- readout 0: en = h1[:,0,:] . w_read0 ----------------
__global__ void k_read0(const float* __restrict__ h1, const float* __restrict__ w0,
                        const int* __restrict__ batch, float* __restrict__ out){
  int t = threadIdx.x; int n = blockIdx.x*4 + (t>>6); int c = t&63;
  float v = h1[(n*9)*64+c]*w0[c];
  v = wsum(v);
  if (c==0){
    int g = batch[n];
    atomicAdd(&out[g], v);
    atomicAdd(&out[G_ + g*3 + 1], v);
  }
}

// ---------------- readout 1: en = silu(h2@Wr1).wr2 ; store spz = silu'(z)*wr2 ----------------
__global__ void k_read1(const float* __restrict__ h2, const float* __restrict__ Wr1,
                        const float* __restrict__ wr2, const int* __restrict__ batch,
                        float* __restrict__ spz, float* __restrict__ out){
  __shared__ float sW[64*16];
  __shared__ float sA[256];
  int t = threadIdx.x;
  for (int i=t;i<1024;i+=256) sW[i]=Wr1[i];
  __syncthreads();
  int n = blockIdx.x*16 + (t>>4); int j = t&15;
  float z = 0.f;
  #pragma unroll 16
  for (int c=0;c<64;++c) z += h2[n*64+c]*sW[c*16+j];
  float sg = sigmoidf_(z);
  float a  = z*sg;
  float sp = sg*(1.0f + z*(1.0f - sg));
  float w2v = wr2[j];
  spz[n*16+j] = sp*w2v;
  sA[t] = a*w2v;
  __syncthreads();
  if (j==0){
    float s = 0.f;
    #pragma unroll
    for (int k=0;k<16;++k) s += sA[t+k];
    int g = batch[n];
    atomicAdd(&out[g], s);
    atomicAdd(&out[G_ + g*3 + 2], s);
  }
}

// ---------------- dh2[n,c] = sum_j Wr1[c,j]*spz[n,j] ----------------
__global__ void k_dh2(const float* __restrict__ Wr1, const float* __restrict__ spz,
                      float* __restrict__ dh2){
  int i = blockIdx.x*256 + threadIdx.x;
  int n = i>>6, c = i&63;
  float acc = 0.f;
  #pragma unroll
  for (int j=0;j<16;++j) acc += Wr1[c*16+j]*spz[n*16+j];
  dh2[i] = acc;
}

// ---------------- fused per-edge backward: dR->dr, dY->du, force scatter ----------------
template<int LAYER>
__global__ void k_bedge(const int* __restrict__ ei, const float* __restrict__ Y,
                        const float* __restrict__ ef, const float* __restrict__ u3,
                        const float* __restrict__ rr, const float* __restrict__ Rbuf,
                        const float* __restrict__ gaBuf, const float* __restrict__ huBuf,
                        const float* __restrict__ W1g, const float* __restrict__ W2g,
                        float* __restrict__ F){
  __shared__ float sW1[8*64];
  __shared__ float sW2[64*65];
  __shared__ float sD[4*64];
  int t = threadIdx.x;
  for (int i=t;i<512;i+=256) sW1[i]=W1g[i];
  for (int i=t;i<4096;i+=256){ int k=i>>6, c=i&63; sW2[k*65+c]=W2g[k*64+c]; }
  __syncthreads();
  int eg = t>>6, c = t&63;
  int e = blockIdx.x*4 + eg;
  int snd = ei[e], rcv = ei[E_+e];
  float dy[9]; dy[0]=0.f;
  float dR;
  if (LAYER==1){
    float T = gaBuf[rcv*64+c];
    float ds = Rbuf[e*64+c]*T;
    float s = 0.f;
    #pragma unroll
    for (int l=0;l<9;++l){
      float h = huBuf[(snd*9+l)*64+c];
      s += h*Y[e*9+l];
      if (l>=1) dy[l] = wsum(ds*h);
    }
    dR = s*T;
  } else {
    float g[9]; float T = 0.f;
    #pragma unroll
    for (int l=0;l<9;++l){ g[l]=gaBuf[(rcv*9+l)*64+c]; T += g[l]*Y[e*9+l]; }
    float s = huBuf[snd*64+c];
    float P = Rbuf[e*64+c]*s;
    dR = s*T;
    #pragma unroll
    for (int l=1;l<9;++l) dy[l] = wsum(g[l]*P);
  }
  // radial backward: recompute z (lane plays role k), dz = sp * (dR . W2[k,:])
  float zpre = 0.f;
  #pragma unroll
  for (int b=0;b<8;++b) zpre += ef[e*8+b]*sW1[b*64+c];
  float sg = sigmoidf_(zpre);
  float sp = sg*(1.0f + zpre*(1.0f - sg));
  sD[eg*64+c] = dR;
  __syncthreads();
  float dz = 0.f;
  #pragma unroll 8
  for (int k=0;k<64;++k) dz += sD[eg*64+k]*sW2[c*65+k];
  dz *= sp;
  float def[8];
  #pragma unroll
  for (int b=0;b<8;++b) def[b] = wsum(dz*sW1[b*64+c]);
  float rad = rr[e]; float invr = 1.0f/rad;
  float term = 0.f;
  if (c < 8){
    float w  = (float)(c+1)*(PI_F/RMAXF);
    float sw = sinf(w*rad), cw = cosf(w*rad);
    float Kc = sqrtf(2.0f/RMAXF);
    float tt = rad*(1.0f/RMAXF);
    float fc = 0.f, dfc = 0.f;
    if (tt < 1.0f){
      float t2=tt*tt, t4=t2*t2, t5=t4*tt, t6=t5*tt, t7=t6*tt, t8=t7*tt;
      fc  = 1.0f - 28.0f*t6 + 48.0f*t7 - 21.0f*t8;
      dfc = (-168.0f*t5 + 336.0f*t6 - 168.0f*t7)*(1.0f/RMAXF);
    }
    float rb  = Kc*sw*invr;
    float drb = Kc*(w*cw - sw*invr)*invr;
    term = def[c]*(drb*fc + rb*dfc);
  }
  float dr = wsum(term);
  float x = u3[e*3+0], y = u3[e*3+1], zz = u3[e*3+2];
  float dux = S3*dy[1] + S15*(y*dy[4] + zz*dy[7] + x*dy[8]);
  float duy = S3*dy[2] + S15*(x*dy[4] + zz*dy[5] - y*dy[8]);
  float duz = S3*dy[3] + S15*(y*dy[5] + x*dy[7]) + 3.0f*S5*zz*dy[6];
  float udot = x*dux + y*duy + zz*duz;
  float gx = dr*x + invr*(dux - x*udot);
  float gy = dr*y + invr*(duy - y*udot);
  float gz = dr*zz + invr*(duz - zz*udot);
  if (c==0){
    atomicAdd(&F[snd*3+0], -gx); atomicAdd(&F[snd*3+1], -gy); atomicAdd(&F[snd*3+2], -gz);
    atomicAdd(&F[rcv*3+0],  gx); atomicAdd(&F[rcv*3+1],  gy); atomicAdd(&F[rcv*3+2],  gz);
  }
}

extern "C" void kernel_launch(void* const* d_in, const int* in_sizes, int n_in,
                              void* d_out, int out_size, void* d_ws, size_t ws_size,
                              hipStream_t stream){
  (void)in_sizes; (void)n_in;
  const float* pos    = (const float*)d_in[0];
  const float* attrs  = (const float*)d_in[1];
  const float* shifts = (const float*)d_in[2];
  const float* ae     = (const float*)d_in[3];
  const float* Wemb   = (const float*)d_in[4];
  const float* Wup    = (const float*)d_in[5];
  const float* W1     = (const float*)d_in[6];
  const float* W2     = (const float*)d_in[7];
  const float* Wout   = (const float*)d_in[8];
  const float* Wskip  = (const float*)d_in[9];
  const float* wread0 = (const float*)d_in[10];
  const float* Wr1    = (const float*)d_in[11];
  const float* wr2    = (const float*)d_in[12];
  const int*   ei     = (const int*)d_in[13];
  const int*   batch  = (const int*)d_in[14];
  float* out = (float*)d_out;

  const size_t NEED = 430000000;
  char* base;
  if (ws_size >= NEED){
    base = (char*)d_ws;
  } else {
    void* p = nullptr;
    hipGetSymbolAddress(&p, HIP_SYMBOL(g_fallback));
    base = (char*)p;
  }
  size_t off = 0;
  auto alloc = [&](size_t nelem)->float*{
    float* p = (float*)(base + off);
    off += ((nelem*sizeof(float) + 255)/256)*256;
    return p;
  };
  float* Y    = alloc((size_t)E_*9);
  float* ef   = alloc((size_t)E_*8);
  float* u3   = alloc((size_t)E_*3);
  float* rr   = alloc((size_t)E_);
  float* R0   = alloc((size_t)E_*64);
  float* R1   = alloc((size_t)E_*64);
  float* hu0  = alloc((size_t)N_*64);
  float* hu1  = alloc((size_t)N_*9*64);
  float* h1   = alloc((size_t)N_*9*64);   // reused as dh1
  float* agg0 = alloc((size_t)N_*9*64);   // reused as dhu1
  float* agg1 = alloc((size_t)N_*64);
  float* h2   = alloc((size_t)N_*64);
  float* spz  = alloc((size_t)N_*16);
  float* dh2  = alloc((size_t)N_*64);
  float* ga1  = alloc((size_t)N_*64);
  float* ga0  = alloc((size_t)N_*9*64);
  float* WembUp = alloc(256);
  int* cnts  = (int*)alloc((size_t)2*N_);          // cntR | cntS
  int* lists = (int*)alloc((size_t)2*N_*CAP);      // listR | listS
  int* cntR = cnts;          int* cntS = cnts + N_;
  int* listR = lists;        int* listS = lists + (size_t)N_*CAP;
  float* dhu1 = agg0;
  float* dh1  = h1;
  float* F = out + G_ + G_*3;

  hipMemsetAsync(d_out, 0, (size_t)out_size*sizeof(float), stream);
  hipMemsetAsync(cnts, 0, (size_t)2*N_*sizeof(int), stream);

  // forward
  k_csr   <<<E_/256, 256, 0, stream>>>(ei, cntR, cntS, listR, listS);
  k_geom  <<<E_/256, 256, 0, stream>>>(pos, shifts, ei, Y, ef, u3, rr);
  k_wembup<<<1, 256, 0, stream>>>(Wemb, Wup, WembUp);
  k_e0    <<<(N_+255)/256, 256, 0, stream>>>(attrs, ae, batch, out);
  k_hu0   <<<N_*64/256, 256, 0, stream>>>(attrs, WembUp, hu0);
  k_R     <<<E_/4, 256, 0, stream>>>(ef, W1,       W2,        R0);
  k_R     <<<E_/4, 256, 0, stream>>>(ef, W1 + 512, W2 + 4096, R1);
  k_agg0  <<<N_/4, 256, 0, stream>>>(cntR, listR, ei, hu0, R0, Y, agg0);
  k_mm64<false><<<N_*9/32, 256, 0, stream>>>(agg0, Wout, h1, N_*9, 9, attrs, Wskip, nullptr);
  k_read0 <<<N_/4, 256, 0, stream>>>(h1, wread0, batch, out);
  k_mm64<false><<<N_*9/32, 256, 0, stream>>>(h1, Wup + 4096, hu1, N_*9, 9, nullptr, nullptr, nullptr);
  k_agg1  <<<N_/4, 256, 0, stream>>>(cntR, listR, ei, hu1, R1, Y, agg1);
  k_mm64<false><<<N_/32, 256, 0, stream>>>(agg1, Wout + 4096, h2, N_, 1, attrs, Wskip + 256, nullptr);
  k_read1 <<<N_/16, 256, 0, stream>>>(h2, Wr1, wr2, batch, spz, out);

  // backward
  k_dh2   <<<N_*64/256, 256, 0, stream>>>(Wr1, spz, dh2);
  k_mm64<true><<<N_/32, 256, 0, stream>>>(dh2, Wout + 4096, ga1, N_, 1, nullptr, nullptr, nullptr);
  k_bedge<1><<<E_/4, 256, 0, stream>>>(ei, Y, ef, u3, rr, R1, ga1, hu1, W1 + 512, W2 + 4096, F);
  k_dhu1  <<<N_/4, 256, 0, stream>>>(cntS, listS, ei, R1, ga1, Y, dhu1);
  k_mm64<true><<<N_*9/32, 256, 0, stream>>>(dhu1, Wup + 4096, dh1, N_*9, 9, nullptr, nullptr, wread0);
  k_mm64<true><<<N_*9/32, 256, 0, stream>>>(dh1, Wout, ga0, N_*9, 9, nullptr, nullptr, nullptr);
  k_bedge<0><<<E_/4, 256, 0, stream>>>(ei, Y, ef, u3, rr, R0, ga0, hu0, W1, W2, F);
}

// Round 2
// 2601.750 us; speedup vs baseline: 1.1537x; 1.1537x over previous
//
#include <hip/hip_runtime.h>
#include <cmath>

constexpr int N_  = 20000;
constexpr int E_  = 320000;
constexpr int NE_ = 4;
constexpr int G_  = 16;
constexpr int CAP = 96;
constexpr float RMAXF = 5.0f;
constexpr float PI_F  = 3.14159265358979323846f;
constexpr float S3  = 1.7320508075688772f;
constexpr float S5  = 2.2360679774997896f;
constexpr float S15 = 3.8729833462074170f;

#define DEV static __device__ __forceinline__

// fallback scratch (440 MB) in case ws_size is too small
__device__ float g_fallback[110000000];

DEV float wsum(float v){
  #pragma unroll
  for (int o = 32; o > 0; o >>= 1) v += __shfl_xor(v, o, 64);
  return v;
}
DEV float sigmoidf_(float x){ return 1.0f/(1.0f+__expf(-x)); }

DEV void ld8(const float* __restrict__ p, float* d){
  float4 a = ((const float4*)p)[0];
  float4 b = ((const float4*)p)[1];
  d[0]=a.x; d[1]=a.y; d[2]=a.z; d[3]=a.w;
  d[4]=b.x; d[5]=b.y; d[6]=b.z; d[7]=b.w;
}
DEV void st8(float* p, const float* d){
  ((float4*)p)[0] = make_float4(d[0],d[1],d[2],d[3]);
  ((float4*)p)[1] = make_float4(d[4],d[5],d[6],d[7]);
}

// ---------------- CSR build (bucket lists, no scan) ----------------
__global__ void k_csr(const int* __restrict__ ei, int* __restrict__ cntR, int* __restrict__ cntS,
                      int* __restrict__ listR, int* __restrict__ listS){
  int e = blockIdx.x*256 + threadIdx.x;
  int s = ei[e], r = ei[E_+e];
  int p = atomicAdd(&cntR[r], 1); if (p < CAP) listR[r*CAP+p] = e;
  int q = atomicAdd(&cntS[s], 1); if (q < CAP) listS[s*CAP+q] = e;
}

// ---------------- geometry: Y, ef, u, r ----------------
__global__ void k_geom(const float* __restrict__ pos, const float* __restrict__ shifts,
                       const int* __restrict__ ei,
                       float* __restrict__ Y, float* __restrict__ ef,
                       float* __restrict__ u3, float* __restrict__ rr){
  int e = blockIdx.x*256 + threadIdx.x;
  int s = ei[e], r = ei[E_+e];
  float vx = pos[s*3+0]-pos[r*3+0]+shifts[e*3+0];
  float vy = pos[s*3+1]-pos[r*3+1]+shifts[e*3+1];
  float vz = pos[s*3+2]-pos[r*3+2]+shifts[e*3+2];
  float ss = vx*vx+vy*vy+vz*vz + 1e-12f;
  float rad = sqrtf(ss);
  float inv = 1.0f/rad;
  float x = vx*inv, y = vy*inv, z = vz*inv;
  u3[e*3+0]=x; u3[e*3+1]=y; u3[e*3+2]=z; rr[e]=rad;
  Y[e*9+0]=1.0f;
  Y[e*9+1]=S3*x;  Y[e*9+2]=S3*y;  Y[e*9+3]=S3*z;
  Y[e*9+4]=S15*x*y; Y[e*9+5]=S15*y*z;
  Y[e*9+6]=0.5f*S5*(3.0f*z*z-1.0f);
  Y[e*9+7]=S15*x*z;
  Y[e*9+8]=0.5f*S15*(x*x-y*y);
  float t = rad*(1.0f/RMAXF);
  float fc = 0.0f;
  if (t < 1.0f){
    float t2=t*t, t4=t2*t2, t6=t4*t2, t7=t6*t, t8=t7*t;
    fc = 1.0f - 28.0f*t6 + 48.0f*t7 - 21.0f*t8;
  }
  float Kc = 0.6324555320336759f; // sqrt(2/RMAX)
  #pragma unroll
  for (int b=0;b<8;++b){
    float w = (float)(b+1)*(PI_F/RMAXF);
    ef[e*8+b] = Kc*__sinf(w*rad)*inv*fc;
  }
}

// ---------------- tiny precompute: WembUp = W_embed @ Wup0 ----------------
__global__ void k_wembup(const float* __restrict__ Wemb, const float* __restrict__ Wup0,
                         float* __restrict__ WembUp){
  int t = threadIdx.x; int k = t>>6, c = t&63;
  float acc = 0.f;
  for (int j=0;j<64;++j) acc += Wemb[k*64+j]*Wup0[j*64+c];
  WembUp[k*64+c] = acc;
}

// ---------------- e0 ----------------
__global__ void k_e0(const float* __restrict__ attrs, const float* __restrict__ ae,
                     const int* __restrict__ batch, float* __restrict__ out){
  int n = blockIdx.x*256 + threadIdx.x; if (n >= N_) return;
  float v = 0.f;
  #pragma unroll
  for (int k=0;k<NE_;++k) v += attrs[n*NE_+k]*ae[k];
  int g = batch[n];
  atomicAdd(&out[g], v);
  atomicAdd(&out[G_ + g*3 + 0], v);
}

// ---------------- hu0 = attrs @ WembUp ----------------
__global__ void k_hu0(const float* __restrict__ attrs, const float* __restrict__ WembUp,
                      float* __restrict__ hu0){
  int i = blockIdx.x*256 + threadIdx.x;
  int n = i>>6, c = i&63;
  float acc = 0.f;
  #pragma unroll
  for (int k=0;k<NE_;++k) acc += attrs[n*NE_+k]*WembUp[k*64+c];
  hu0[i] = acc;
}

// ---------------- R = silu(ef@W1) @ W2 ; 8 lanes/edge, 8 edges/wave ----------------
__global__ void k_R(const float* __restrict__ ef, const float* __restrict__ W1g,
                    const float* __restrict__ W2g, float* __restrict__ R){
  __shared__ float sW1[512];
  __shared__ float sW2[4096];
  __shared__ float sA[4*544];
  int t = threadIdx.x;
  for (int i=t;i<512;i+=256)  sW1[i]=W1g[i];
  for (int i=t;i<4096;i+=256) sW2[i]=W2g[i];
  __syncthreads();
  int wid=t>>6, lane=t&63, q=lane>>3, j=lane&7, c0=j*8;
  int e = blockIdx.x*32 + wid*8 + q;
  float z[8]={0,0,0,0,0,0,0,0};
  #pragma unroll
  for (int b=0;b<8;++b){
    float efb = ef[(size_t)e*8+b];
    const float4* w=(const float4*)(sW1 + b*64 + c0);
    float4 wa=w[0], wb=w[1];
    z[0]+=efb*wa.x; z[1]+=efb*wa.y; z[2]+=efb*wa.z; z[3]+=efb*wa.w;
    z[4]+=efb*wb.x; z[5]+=efb*wb.y; z[6]+=efb*wb.z; z[7]+=efb*wb.w;
  }
  float a[8];
  #pragma unroll
  for (int i=0;i<8;++i) a[i] = z[i]*sigmoidf_(z[i]);
  float* myA = sA + wid*544 + q*68;
  st8(myA + c0, a);
  float racc[8]={0,0,0,0,0,0,0,0};
  #pragma unroll
  for (int kk=0;kk<16;++kk){
    float4 a4 = ((const float4*)myA)[kk];
    #pragma unroll
    for (int mm=0;mm<4;++mm){
      float ak = (mm==0)?a4.x:(mm==1)?a4.y:(mm==2)?a4.z:a4.w;
      const float4* w=(const float4*)(sW2 + (4*kk+mm)*64 + c0);
      float4 wa=w[0], wb=w[1];
      racc[0]+=ak*wa.x; racc[1]+=ak*wa.y; racc[2]+=ak*wa.z; racc[3]+=ak*wa.w;
      racc[4]+=ak*wb.x; racc[5]+=ak*wb.y; racc[6]+=ak*wb.z; racc[7]+=ak*wb.w;
    }
  }
  st8(R + (size_t)e*64 + c0, racc);
}

// ---------------- agg0[n,l,c] = sum_e Y[e,l]*R0[e,c]*hu0[snd,c]  (wave/node) ----------------
__global__ void k_agg0(const int* __restrict__ cntR, const int* __restrict__ listR,
                       const int* __restrict__ ei, const float* __restrict__ hu0,
                       const float* __restrict__ R0, const float* __restrict__ Y,
                       float* __restrict__ agg0){
  int t = threadIdx.x; int n = blockIdx.x*4 + (t>>6); int c = t&63;
  float acc[9] = {0,0,0,0,0,0,0,0,0};
  int deg = min(cntR[n], CAP);
  for (int j=0;j<deg;++j){
    int e = listR[n*CAP+j];
    int s = ei[e];
    float p = R0[e*64+c]*hu0[s*64+c];
    #pragma unroll
    for (int l=0;l<9;++l) acc[l] += Y[e*9+l]*p;
  }
  #pragma unroll
  for (int l=0;l<9;++l) agg0[(n*9+l)*64+c] = acc[l];
}

// ---------------- agg1[n,c] = sum_e R1[e,c]*s1[e,c] (s1 computed on the fly) ----------------
__global__ void k_agg1(const int* __restrict__ cntR, const int* __restrict__ listR,
                       const int* __restrict__ ei, const float* __restrict__ hu1,
                       const float* __restrict__ R1, const float* __restrict__ Y,
                       float* __restrict__ agg1){
  int t = threadIdx.x; int n = blockIdx.x*4 + (t>>6); int c = t&63;
  float acc = 0.f;
  int deg = min(cntR[n], CAP);
  for (int j=0;j<deg;++j){
    int e = listR[n*CAP+j];
    int s = ei[e];
    float sacc = 0.f;
    #pragma unroll
    for (int l=0;l<9;++l) sacc += hu1[(s*9+l)*64+c]*Y[e*9+l];
    acc += R1[e*64+c]*sacc;
  }
  agg1[n*64+c] = acc;
}

// ---------------- dhu1[n,l,c] = sum_{snd-list} Y[e,l]*R1[e,c]*ga1[rcv,c] ----------------
__global__ void k_dhu1(const int* __restrict__ cntS, const int* __restrict__ listS,
                       const int* __restrict__ ei, const float* __restrict__ R1,
                       const float* __restrict__ ga1, const float* __restrict__ Y,
                       float* __restrict__ dhu1){
  int t = threadIdx.x; int n = blockIdx.x*4 + (t>>6); int c = t&63;
  float acc[9] = {0,0,0,0,0,0,0,0,0};
  int deg = min(cntS[n], CAP);
  for (int j=0;j<deg;++j){
    int e = listS[n*CAP+j];
    int r = ei[E_+e];
    float ds = R1[e*64+c]*ga1[r*64+c];
    #pragma unroll
    for (int l=0;l<9;++l) acc[l] += Y[e*9+l]*ds;
  }
  #pragma unroll
  for (int l=0;l<9;++l) dhu1[(n*9+l)*64+c] = acc[l];
}

// ---------------- generic 64x64 row-matmul, optional transpose/skip/bias ----------------
template<bool TRANS>
__global__ void k_mm64(const float* __restrict__ in, const float* __restrict__ W,
                       float* __restrict__ out, int rows, int lper,
                       const float* __restrict__ attrs, const float* __restrict__ Wsk,
                       const float* __restrict__ bias){
  __shared__ float sW[64*65];
  __shared__ float sRow[4*64];
  int t = threadIdx.x;
  for (int i=t;i<4096;i+=256){
    int k=i>>6, c=i&63;
    sW[k*65+c] = TRANS ? W[c*64+k] : W[k*64+c];
  }
  __syncthreads();
  int wid = t>>6, c = t&63;
  for (int it=0; it<8; ++it){
    int row = (blockIdx.x*8+it)*4 + wid;
    sRow[wid*64+c] = in[row*64+c];          // wave-private slice: no barrier needed
    float acc = 0.f;
    #pragma unroll 16
    for (int k=0;k<64;++k) acc += sRow[wid*64+k]*sW[k*65+c];
    if (lper==1 || (row % 9)==0){
      int n = (lper==1) ? row : (row/9);
      if (attrs){
        #pragma unroll
        for (int k=0;k<NE_;++k) acc += attrs[n*NE_+k]*Wsk[k*64+c];
      }
      if (bias) acc += bias[c];
    }
    out[row*64+c] = acc;
  }
}

// ---------------- readout 0: en = h1[:,0,:] . w_read0 ----------------
__global__ void k_read0(const float* __restrict__ h1, const float* __restrict__ w0,
                        const int* __restrict__ batch, float* __restrict__ out){
  int t = threadIdx.x; int n = blockIdx.x*4 + (t>>6); int c = t&63;
  float v = h1[(n*9)*64+c]*w0[c];
  v = wsum(v);
  if (c==0){
    int g = batch[n];
    atomicAdd(&out[g], v);
    atomicAdd(&out[G_ + g*3 + 1], v);
  }
}

// ---------------- readout 1: en = silu(h2@Wr1).wr2 ; store spz = silu'(z)*wr2 ----------------
__global__ void k_read1(const float* __restrict__ h2, const float* __restrict__ Wr1,
                        const float* __restrict__ wr2, const int* __restrict__ batch,
                        float* __restrict__ spz, float* __restrict__ out){
  __shared__ float sW[64*16];
  __shared__ float sA[256];
  int t = threadIdx.x;
  for (int i=t;i<1024;i+=256) sW[i]=Wr1[i];
  __syncthreads();
  int n = blockIdx.x*16 + (t>>4); int j = t&15;
  float z = 0.f;
  #pragma unroll 16
  for (int c=0;c<64;++c) z += h2[n*64+c]*sW[c*16+j];
  float sg = sigmoidf_(z);
  float a  = z*sg;
  float sp = sg*(1.0f + z*(1.0f - sg));
  float w2v = wr2[j];
  spz[n*16+j] = sp*w2v;
  sA[t] = a*w2v;
  __syncthreads();
  if (j==0){
    float s = 0.f;
    #pragma unroll
    for (int k=0;k<16;++k) s += sA[t+k];
    int g = batch[n];
    atomicAdd(&out[g], s);
    atomicAdd(&out[G_ + g*3 + 2], s);
  }
}

// ---------------- dh2[n,c] = sum_j Wr1[c,j]*spz[n,j] ----------------
__global__ void k_dh2(const float* __restrict__ Wr1, const float* __restrict__ spz,
                      float* __restrict__ dh2){
  int i = blockIdx.x*256 + threadIdx.x;
  int n = i>>6, c = i&63;
  float acc = 0.f;
  #pragma unroll
  for (int j=0;j<16;++j) acc += Wr1[c*16+j]*spz[n*16+j];
  dh2[i] = acc;
}

// ---------------- fused per-edge backward: 8 lanes/edge, 8 edges/wave ----------------
template<int LAYER>
__global__ void k_bedge(const int* __restrict__ ei, const float* __restrict__ Y,
                        const float* __restrict__ ef, const float* __restrict__ u3,
                        const float* __restrict__ rr, const float* __restrict__ Rbuf,
                        const float* __restrict__ gaBuf, const float* __restrict__ huBuf,
                        const float* __restrict__ W1g, const float* __restrict__ W2g,
                        float* __restrict__ F){
  __shared__ float sW1[512];
  __shared__ float sW2T[4096];   // sW2T[m*64+c] = W2[c,m]
  __shared__ float sDR[4*544];
  int t = threadIdx.x;
  for (int i=t;i<512;i+=256)  sW1[i]=W1g[i];
  for (int i=t;i<4096;i+=256) sW2T[i] = W2g[(i&63)*64 + (i>>6)];
  __syncthreads();
  int wid=t>>6, lane=t&63, q=lane>>3, j=lane&7, c0=j*8;
  int e = blockIdx.x*32 + wid*8 + q;
  int snd = ei[e], rcv = ei[E_+e];
  float dyp[9];
  float dR[8];
  if (LAYER==1){
    float T[8], ds[8], s[8], hu[8];
    ld8(gaBuf + (size_t)rcv*64 + c0, T);
    ld8(Rbuf + (size_t)e*64 + c0, ds);
    #pragma unroll
    for (int i=0;i<8;++i){ ds[i]*=T[i]; s[i]=0.f; }
    #pragma unroll
    for (int l=0;l<9;++l){
      float Yl = Y[e*9+l];
      ld8(huBuf + ((size_t)snd*9 + l)*64 + c0, hu);
      float p=0.f;
      #pragma unroll
      for (int i=0;i<8;++i){ s[i] += hu[i]*Yl; p += ds[i]*hu[i]; }
      dyp[l]=p;
    }
    #pragma unroll
    for (int i=0;i<8;++i) dR[i]=s[i]*T[i];
  } else {
    float s[8], P[8], T[8], g[8];
    ld8(huBuf + (size_t)snd*64 + c0, s);
    ld8(Rbuf + (size_t)e*64 + c0, P);
    #pragma unroll
    for (int i=0;i<8;++i){ P[i]*=s[i]; T[i]=0.f; }
    #pragma unroll
    for (int l=0;l<9;++l){
      float Yl = Y[e*9+l];
      ld8(gaBuf + ((size_t)rcv*9 + l)*64 + c0, g);
      float p=0.f;
      #pragma unroll
      for (int i=0;i<8;++i){ T[i]+=g[i]*Yl; p += g[i]*P[i]; }
      dyp[l]=p;
    }
    #pragma unroll
    for (int i=0;i<8;++i) dR[i]=s[i]*T[i];
  }
  float dy[9];
  #pragma unroll
  for (int l=1;l<9;++l){
    float v=dyp[l];
    v += __shfl_xor(v,1,64); v += __shfl_xor(v,2,64); v += __shfl_xor(v,4,64);
    dy[l]=v;
  }
  // radial backward: z = ef@W1, sp = silu'(z)
  float z[8]={0,0,0,0,0,0,0,0};
  #pragma unroll
  for (int b=0;b<8;++b){
    float efb = ef[(size_t)e*8+b];
    const float4* w=(const float4*)(sW1 + b*64 + c0);
    float4 wa=w[0], wb=w[1];
    z[0]+=efb*wa.x; z[1]+=efb*wa.y; z[2]+=efb*wa.z; z[3]+=efb*wa.w;
    z[4]+=efb*wb.x; z[5]+=efb*wb.y; z[6]+=efb*wb.z; z[7]+=efb*wb.w;
  }
  float sp[8];
  #pragma unroll
  for (int i=0;i<8;++i){
    float sg = sigmoidf_(z[i]);
    sp[i] = sg*(1.0f + z[i]*(1.0f-sg));
  }
  // dzraw[c] = sum_m dR[m] * W2[c,m]  via LDS-staged dR (broadcast within edge)
  float* myDR = sDR + wid*544 + q*68;
  st8(myDR + c0, dR);
  float dzr[8]={0,0,0,0,0,0,0,0};
  #pragma unroll
  for (int kk=0;kk<16;++kk){
    float4 d4 = ((const float4*)myDR)[kk];
    #pragma unroll
    for (int mm=0;mm<4;++mm){
      float dm = (mm==0)?d4.x:(mm==1)?d4.y:(mm==2)?d4.z:d4.w;
      const float4* w=(const float4*)(sW2T + (4*kk+mm)*64 + c0);
      float4 wa=w[0], wb=w[1];
      dzr[0]+=dm*wa.x; dzr[1]+=dm*wa.y; dzr[2]+=dm*wa.z; dzr[3]+=dm*wa.w;
      dzr[4]+=dm*wb.x; dzr[5]+=dm*wb.y; dzr[6]+=dm*wb.z; dzr[7]+=dm*wb.w;
    }
  }
  float dzv[8];
  #pragma unroll
  for (int i=0;i<8;++i) dzv[i] = sp[i]*dzr[i];
  // def[b] = sum_c W1[b,c]*dz[c]
  float defp[8];
  #pragma unroll
  for (int b=0;b<8;++b){
    const float4* w=(const float4*)(sW1 + b*64 + c0);
    float4 wa=w[0], wb=w[1];
    float p = dzv[0]*wa.x + dzv[1]*wa.y + dzv[2]*wa.z + dzv[3]*wa.w
            + dzv[4]*wb.x + dzv[5]*wb.y + dzv[6]*wb.z + dzv[7]*wb.w;
    p += __shfl_xor(p,1,64); p += __shfl_xor(p,2,64); p += __shfl_xor(p,4,64);
    defp[b]=p;
  }
  // dr: lane handles basis b=j
  float rad = rr[e]; float invr = 1.0f/rad;
  float w  = (float)(j+1)*(PI_F/RMAXF);
  float sw = __sinf(w*rad), cw = __cosf(w*rad);
  float Kc = 0.6324555320336759f;
  float tt = rad*(1.0f/RMAXF);
  float fc = 0.f, dfc = 0.f;
  if (tt < 1.0f){
    float t2=tt*tt, t4=t2*t2, t5=t4*tt, t6=t5*tt, t7=t6*tt, t8=t7*tt;
    fc  = 1.0f - 28.0f*t6 + 48.0f*t7 - 21.0f*t8;
    dfc = (-168.0f*t5 + 336.0f*t6 - 168.0f*t7)*(1.0f/RMAXF);
  }
  float rb  = Kc*sw*invr;
  float drb = Kc*(w*cw - sw*invr)*invr;
  float term = defp[j]*(drb*fc + rb*dfc);
  term += __shfl_xor(term,1,64); term += __shfl_xor(term,2,64); term += __shfl_xor(term,4,64);
  float dr = term;
  float x = u3[e*3+0], y = u3[e*3+1], zz = u3[e*3+2];
  float dux = S3*dy[1] + S15*(y*dy[4] + zz*dy[7] + x*dy[8]);
  float duy = S3*dy[2] + S15*(x*dy[4] + zz*dy[5] - y*dy[8]);
  float duz = S3*dy[3] + S15*(y*dy[5] + x*dy[7]) + 3.0f*S5*zz*dy[6];
  float udot = x*dux + y*duy + zz*duz;
  float gx = dr*x + invr*(dux - x*udot);
  float gy = dr*y + invr*(duy - y*udot);
  float gz = dr*zz + invr*(duz - zz*udot);
  if (j==0){
    atomicAdd(&F[snd*3+0], -gx); atomicAdd(&F[snd*3+1], -gy); atomicAdd(&F[snd*3+2], -gz);
    atomicAdd(&F[rcv*3+0],  gx); atomicAdd(&F[rcv*3+1],  gy); atomicAdd(&F[rcv*3+2],  gz);
  }
}

extern "C" void kernel_launch(void* const* d_in, const int* in_sizes, int n_in,
                              void* d_out, int out_size, void* d_ws, size_t ws_size,
                              hipStream_t stream){
  (void)in_sizes; (void)n_in;
  const float* pos    = (const float*)d_in[0];
  const float* attrs  = (const float*)d_in[1];
  const float* shifts = (const float*)d_in[2];
  const float* ae     = (const float*)d_in[3];
  const float* Wemb   = (const float*)d_in[4];
  const float* Wup    = (const float*)d_in[5];
  const float* W1     = (const float*)d_in[6];
  const float* W2     = (const float*)d_in[7];
  const float* Wout   = (const float*)d_in[8];
  const float* Wskip  = (const float*)d_in[9];
  const float* wread0 = (const float*)d_in[10];
  const float* Wr1    = (const float*)d_in[11];
  const float* wr2    = (const float*)d_in[12];
  const int*   ei     = (const int*)d_in[13];
  const int*   batch  = (const int*)d_in[14];
  float* out = (float*)d_out;

  const size_t NEED = 430000000;
  char* base;
  if (ws_size >= NEED){
    base = (char*)d_ws;
  } else {
    void* p = nullptr;
    hipGetSymbolAddress(&p, HIP_SYMBOL(g_fallback));
    base = (char*)p;
  }
  size_t off = 0;
  auto alloc = [&](size_t nelem)->float*{
    float* p = (float*)(base + off);
    off += ((nelem*sizeof(float) + 255)/256)*256;
    return p;
  };
  float* Y    = alloc((size_t)E_*9);
  float* ef   = alloc((size_t)E_*8);
  float* u3   = alloc((size_t)E_*3);
  float* rr   = alloc((size_t)E_);
  float* R0   = alloc((size_t)E_*64);
  float* R1   = alloc((size_t)E_*64);
  float* hu0  = alloc((size_t)N_*64);
  float* hu1  = alloc((size_t)N_*9*64);
  float* h1   = alloc((size_t)N_*9*64);   // reused as dh1
  float* agg0 = alloc((size_t)N_*9*64);   // reused as dhu1
  float* agg1 = alloc((size_t)N_*64);
  float* h2   = alloc((size_t)N_*64);
  float* spz  = alloc((size_t)N_*16);
  float* dh2  = alloc((size_t)N_*64);
  float* ga1  = alloc((size_t)N_*64);
  float* ga0  = alloc((size_t)N_*9*64);
  float* WembUp = alloc(256);
  int* cnts  = (int*)alloc((size_t)2*N_);          // cntR | cntS
  int* lists = (int*)alloc((size_t)2*N_*CAP);      // listR | listS
  int* cntR = cnts;          int* cntS = cnts + N_;
  int* listR = lists;        int* listS = lists + (size_t)N_*CAP;
  float* dhu1 = agg0;
  float* dh1  = h1;
  float* F = out + G_ + G_*3;

  hipMemsetAsync(d_out, 0, (size_t)out_size*sizeof(float), stream);
  hipMemsetAsync(cnts, 0, (size_t)2*N_*sizeof(int), stream);

  // forward
  k_csr   <<<E_/256, 256, 0, stream>>>(ei, cntR, cntS, listR, listS);
  k_geom  <<<E_/256, 256, 0, stream>>>(pos, shifts, ei, Y, ef, u3, rr);
  k_wembup<<<1, 256, 0, stream>>>(Wemb, Wup, WembUp);
  k_e0    <<<(N_+255)/256, 256, 0, stream>>>(attrs, ae, batch, out);
  k_hu0   <<<N_*64/256, 256, 0, stream>>>(attrs, WembUp, hu0);
  k_R     <<<E_/32, 256, 0, stream>>>(ef, W1,       W2,        R0);
  k_R     <<<E_/32, 256, 0, stream>>>(ef, W1 + 512, W2 + 4096, R1);
  k_agg0  <<<N_/4, 256, 0, stream>>>(cntR, listR, ei, hu0, R0, Y, agg0);
  k_mm64<false><<<N_*9/32, 256, 0, stream>>>(agg0, Wout, h1, N_*9, 9, attrs, Wskip, nullptr);
  k_read0 <<<N_/4, 256, 0, stream>>>(h1, wread0, batch, out);
  k_mm64<false><<<N_*9/32, 256, 0, stream>>>(h1, Wup + 4096, hu1, N_*9, 9, nullptr, nullptr, nullptr);
  k_agg1  <<<N_/4, 256, 0, stream>>>(cntR, listR, ei, hu1, R1, Y, agg1);
  k_mm64<false><<<N_/32, 256, 0, stream>>>(agg1, Wout + 4096, h2, N_, 1, attrs, Wskip + 256, nullptr);
  k_read1 <<<N_/16, 256, 0, stream>>>(h2, Wr1, wr2, batch, spz, out);

  // backward
  k_dh2   <<<N_*64/256, 256, 0, stream>>>(Wr1, spz, dh2);
  k_mm64<true><<<N_/32, 256, 0, stream>>>(dh2, Wout + 4096, ga1, N_, 1, nullptr, nullptr, nullptr);
  k_bedge<1><<<E_/32, 256, 0, stream>>>(ei, Y, ef, u3, rr, R1, ga1, hu1, W1 + 512, W2 + 4096, F);
  k_dhu1  <<<N_/4, 256, 0, stream>>>(cntS, listS, ei, R1, ga1, Y, dhu1);
  k_mm64<true><<<N_*9/32, 256, 0, stream>>>(dhu1, Wup + 4096, dh1, N_*9, 9, nullptr, nullptr, wread0);
  k_mm64<true><<<N_*9/32, 256, 0, stream>>>(dh1, Wout, ga0, N_*9, 9, nullptr, nullptr, nullptr);
  k_bedge<0><<<E_/32, 256, 0, stream>>>(ei, Y, ef, u3, rr, R0, ga0, hu0, W1, W2, F);
}